// Round 1
// baseline (882.425 us; speedup 1.0000x reference)
//
#include <hip/hip_runtime.h>
#include <math.h>

#define NN 100000
#define EE 1600000
#define ETOT 1700000
#define MM 20000
#define GG 512

static constexpr int NB_N256 = (NN + 255) / 256;    // 391
static constexpr int NB_E256 = (ETOT + 255) / 256;  // 6641
static constexpr int NB_AGG  = NN / 32;             // 3125

// small-buffer layout (float indices)
#define SM_MEAN 0
#define SM_WEA 16
#define SM_VS4 272
#define SM_VD4 400
#define SM_W4P 528
#define SM_TOTAL 8720

__device__ __forceinline__ unsigned short f2bf(float f) {
  unsigned int u = __float_as_uint(f);
  u += 0x7fffu + ((u >> 16) & 1u);
  return (unsigned short)(u >> 16);
}
__device__ __forceinline__ float bf2f(unsigned short h) {
  return __uint_as_float(((unsigned int)h) << 16);
}
__device__ __forceinline__ float lrelu(float v, float s) { return v > 0.f ? v : s * v; }

// ---- edge_attr mean (partial sums via atomics; divided by E in k_pre) ----
__global__ __launch_bounds__(256) void k_eamean(const float* __restrict__ ea,
                                                float* __restrict__ sm) {
  __shared__ float lsum[16];
  int t = threadIdx.x;
  if (t < 16) lsum[t] = 0.f;
  __syncthreads();
  int d = t & 15;
  float local = 0.f;
  size_t total = (size_t)EE * 16;
  for (size_t i = (size_t)blockIdx.x * blockDim.x + t; i < total;
       i += (size_t)gridDim.x * blockDim.x)
    local += ea[i];
  atomicAdd(&lsum[d], local);
  __syncthreads();
  if (t < 16) atomicAdd(&sm[SM_MEAN + t], lsum[t]);
}

// ---- CSR: degree count ----
__global__ __launch_bounds__(256) void k_count(const int* __restrict__ ei,
                                               int* __restrict__ counts) {
  int e = blockIdx.x * 256 + threadIdx.x;
  if (e >= ETOT) return;
  int dst = (e < EE) ? ei[EE + e] : (e - EE);
  atomicAdd(&counts[dst], 1);
}

// ---- 3-phase exclusive scan over N ----
__global__ __launch_bounds__(256) void k_scan1(const int* __restrict__ counts,
                                               int* __restrict__ excl,
                                               int* __restrict__ bsum) {
  __shared__ int s[256];
  int t = threadIdx.x, i = blockIdx.x * 256 + t;
  int v = (i < NN) ? counts[i] : 0;
  s[t] = v;
  __syncthreads();
  for (int off = 1; off < 256; off <<= 1) {
    int x = (t >= off) ? s[t - off] : 0;
    __syncthreads();
    s[t] += x;
    __syncthreads();
  }
  if (i < NN) excl[i] = s[t] - v;
  if (t == 255) bsum[blockIdx.x] = s[255];
}

__global__ __launch_bounds__(512) void k_scan2(int* __restrict__ bsum) {
  __shared__ int s[512];
  int t = threadIdx.x;
  int v = (t < NB_N256) ? bsum[t] : 0;
  s[t] = v;
  __syncthreads();
  for (int off = 1; off < 512; off <<= 1) {
    int x = (t >= off) ? s[t - off] : 0;
    __syncthreads();
    s[t] += x;
    __syncthreads();
  }
  if (t < NB_N256) bsum[t] = s[t] - v;
}

__global__ __launch_bounds__(256) void k_scan3(int* __restrict__ row_off,
                                               int* __restrict__ cursor,
                                               const int* __restrict__ bsum) {
  int i = blockIdx.x * 256 + threadIdx.x;
  if (i < NN) {
    int r = row_off[i] + bsum[blockIdx.x];
    row_off[i] = r;
    cursor[i] = r;
  }
  if (i == 0) row_off[NN] = ETOT;
}

// ---- precompute reduced weights ----
__global__ __launch_bounds__(256) void k_pre(
    float* __restrict__ sm, const float* __restrict__ We1, const float* __restrict__ We2,
    const float* __restrict__ We3, const float* __restrict__ We4,
    const float* __restrict__ ae1, const float* __restrict__ ae2,
    const float* __restrict__ ae3, const float* __restrict__ ae4,
    const float* __restrict__ as4, const float* __restrict__ ad4,
    const float* __restrict__ W4) {
  int t = threadIdx.x;
  if (t < 16) sm[SM_MEAN + t] *= (1.f / EE);
  // Wea[l][d][h] = sum_c We_l[d, h*C+c] * ae_l[h,c]
  {
    int l = t >> 6, d = (t >> 2) & 15, h = t & 3;
    const float* We = (l == 0) ? We1 : (l == 1) ? We2 : (l == 2) ? We3 : We4;
    const float* ae = (l == 0) ? ae1 : (l == 1) ? ae2 : (l == 2) ? ae3 : ae4;
    int C = (l == 3) ? 64 : 8;
    float s = 0.f;
    for (int c = 0; c < C; c++) s += We[d * (4 * C) + h * C + c] * ae[h * C + c];
    sm[SM_WEA + l * 64 + d * 4 + h] = s;
  }
  // Vs4/Vd4 [32][4]
  if (t < 128) {
    int k = t >> 2, h = t & 3;
    float s1 = 0.f, s2 = 0.f;
    for (int c = 0; c < 64; c++) {
      float w = W4[k * 256 + h * 64 + c];
      s1 += w * as4[h * 64 + c];
      s2 += w * ad4[h * 64 + c];
    }
    sm[SM_VS4 + t] = s1;
    sm[SM_VD4 + t] = s2;
  }
  // W4p[h*32+k][c] = 0.25 * W4[k, h*64+c]
  for (int i = t; i < 8192; i += 256) {
    int row = i >> 6, c = i & 63;
    int h = row >> 5, k = row & 31;
    sm[SM_W4P + i] = 0.25f * W4[k * 256 + h * 64 + c];
  }
}

// ---- CSR fill + per-edge attention logit contributions (bf16, 4 layers) ----
__global__ __launch_bounds__(256) void k_fill(const int* __restrict__ ei,
                                              const float* __restrict__ ea,
                                              const float* __restrict__ sm,
                                              int* __restrict__ cursor,
                                              int* __restrict__ csr_src,
                                              unsigned long long* __restrict__ aepack) {
  __shared__ float sWea[256];
  __shared__ float smean[16];
  int t = threadIdx.x;
  sWea[t] = sm[SM_WEA + t];
  if (t < 16) smean[t] = sm[SM_MEAN + t];
  __syncthreads();
  int e = blockIdx.x * 256 + t;
  if (e >= ETOT) return;
  int src, dst;
  float eav[16];
  if (e < EE) {
    src = ei[e];
    dst = ei[EE + e];
    const float4* p = (const float4*)(ea + (size_t)e * 16);
    float4 v0 = p[0], v1 = p[1], v2 = p[2], v3 = p[3];
    eav[0] = v0.x; eav[1] = v0.y; eav[2] = v0.z; eav[3] = v0.w;
    eav[4] = v1.x; eav[5] = v1.y; eav[6] = v1.z; eav[7] = v1.w;
    eav[8] = v2.x; eav[9] = v2.y; eav[10] = v2.z; eav[11] = v2.w;
    eav[12] = v3.x; eav[13] = v3.y; eav[14] = v3.z; eav[15] = v3.w;
  } else {
    src = dst = e - EE;
#pragma unroll
    for (int d = 0; d < 16; d++) eav[d] = smean[d];
  }
  int pos = atomicAdd(&cursor[dst], 1);
  csr_src[pos] = src;
#pragma unroll
  for (int l = 0; l < 4; l++) {
    unsigned long long pk = 0;
#pragma unroll
    for (int h = 0; h < 4; h++) {
      float s = 0.f;
#pragma unroll
      for (int d = 0; d < 16; d++) s += eav[d] * sWea[l * 64 + d * 4 + h];
      pk |= (unsigned long long)f2bf(s) << (16 * h);
    }
    aepack[(size_t)l * ETOT + pos] = pk;
  }
}

// ---- node transform: hx = in@W, alpha_src/dst reductions ----
template <int DIN>
__global__ __launch_bounds__(256) void k_t(const float* __restrict__ in,
                                           const float* __restrict__ W,
                                           const float* __restrict__ a_s,
                                           const float* __restrict__ a_d,
                                           float* __restrict__ hx,
                                           float* __restrict__ ssrc,
                                           float* __restrict__ sdst) {
  __shared__ float4 sW[DIN * 8];
  __shared__ float sas[32], sad[32];
  int t = threadIdx.x;
  for (int i = t; i < DIN * 8; i += 256) sW[i] = ((const float4*)W)[i];
  if (t < 32) { sas[t] = a_s[t]; sad[t] = a_d[t]; }
  __syncthreads();
  int n = blockIdx.x * 256 + t;
  if (n >= NN) return;
  float acc[32];
#pragma unroll
  for (int j = 0; j < 32; j++) acc[j] = 0.f;
  const float* xr = in + (size_t)n * DIN;
  for (int k = 0; k < DIN; k += 4) {
    float4 xv = *(const float4*)(xr + k);
    float xa[4] = {xv.x, xv.y, xv.z, xv.w};
#pragma unroll
    for (int kk = 0; kk < 4; kk++) {
#pragma unroll
      for (int j4 = 0; j4 < 8; j4++) {
        float4 ww = sW[(k + kk) * 8 + j4];
        acc[j4 * 4 + 0] += xa[kk] * ww.x;
        acc[j4 * 4 + 1] += xa[kk] * ww.y;
        acc[j4 * 4 + 2] += xa[kk] * ww.z;
        acc[j4 * 4 + 3] += xa[kk] * ww.w;
      }
    }
  }
  float ssum[4], dsum[4];
#pragma unroll
  for (int h = 0; h < 4; h++) {
    float s = 0.f, d = 0.f;
#pragma unroll
    for (int c = 0; c < 8; c++) {
      s += acc[h * 8 + c] * sas[h * 8 + c];
      d += acc[h * 8 + c] * sad[h * 8 + c];
    }
    ssum[h] = s;
    dsum[h] = d;
  }
  float* hr = hx + (size_t)n * 32;
#pragma unroll
  for (int j4 = 0; j4 < 8; j4++)
    ((float4*)hr)[j4] =
        make_float4(acc[j4 * 4], acc[j4 * 4 + 1], acc[j4 * 4 + 2], acc[j4 * 4 + 3]);
  ((float4*)ssrc)[n] = make_float4(ssum[0], ssum[1], ssum[2], ssum[3]);
  ((float4*)sdst)[n] = make_float4(dsum[0], dsum[1], dsum[2], dsum[3]);
}

// ---- layer-4 attention reductions only ----
__global__ __launch_bounds__(256) void k_t4(const float* __restrict__ h3,
                                            const float* __restrict__ sm,
                                            float* __restrict__ ssrc,
                                            float* __restrict__ sdst) {
  __shared__ float sVs[128], sVd[128];
  int t = threadIdx.x;
  if (t < 128) { sVs[t] = sm[SM_VS4 + t]; sVd[t] = sm[SM_VD4 + t]; }
  __syncthreads();
  int n = blockIdx.x * 256 + t;
  if (n >= NN) return;
  const float* r = h3 + (size_t)n * 32;
  float s0 = 0, s1 = 0, s2 = 0, s3 = 0, d0 = 0, d1 = 0, d2 = 0, d3 = 0;
#pragma unroll
  for (int k = 0; k < 32; k++) {
    float v = r[k];
    s0 += v * sVs[k * 4 + 0]; s1 += v * sVs[k * 4 + 1];
    s2 += v * sVs[k * 4 + 2]; s3 += v * sVs[k * 4 + 3];
    d0 += v * sVd[k * 4 + 0]; d1 += v * sVd[k * 4 + 1];
    d2 += v * sVd[k * 4 + 2]; d3 += v * sVd[k * 4 + 3];
  }
  ((float4*)ssrc)[n] = make_float4(s0, s1, s2, s3);
  ((float4*)sdst)[n] = make_float4(d0, d1, d2, d3);
}

// ---- layers 1-3 aggregation: 8 lanes/node, online softmax, fused epilogue ----
__global__ __launch_bounds__(256) void k_agg(const int* __restrict__ row_off,
                                             const int* __restrict__ csr_src,
                                             const unsigned long long* __restrict__ aepack,
                                             const float* __restrict__ hx,
                                             const float* __restrict__ ssrc,
                                             const float* __restrict__ sdst,
                                             const float* __restrict__ bias,
                                             float* __restrict__ outp) {
  int t = threadIdx.x;
  int g = t >> 3, j = t & 7, h = j >> 1;
  int n = blockIdx.x * 32 + g;
  if (n >= NN) return;
  float sd = sdst[n * 4 + h];
  int e0 = row_off[n], e1 = row_off[n + 1];
  float m = -1e30f, den = 0.f;
  float4 acc = make_float4(0.f, 0.f, 0.f, 0.f);
  for (int e = e0; e < e1; ++e) {
    int src = csr_src[e];
    unsigned long long pk = aepack[e];
    float ae = bf2f((unsigned short)(pk >> (16 * h)));
    float al = ssrc[src * 4 + h] + sd + ae;
    al = lrelu(al, 0.2f);
    float4 hv = *(const float4*)(hx + (size_t)src * 32 + (j << 2));
    float nm = fmaxf(m, al);
    float c1 = __expf(m - nm);
    float p = __expf(al - nm);
    den = den * c1 + p;
    acc.x = acc.x * c1 + p * hv.x;
    acc.y = acc.y * c1 + p * hv.y;
    acc.z = acc.z * c1 + p * hv.z;
    acc.w = acc.w * c1 + p * hv.w;
    m = nm;
  }
  float inv = 1.f / (den + 1e-16f);
  float4 b = *(const float4*)(bias + (j << 2));
  float4 o;
  o.x = lrelu(acc.x * inv + b.x, 0.01f);
  o.y = lrelu(acc.y * inv + b.y, 0.01f);
  o.z = lrelu(acc.z * inv + b.z, 0.01f);
  o.w = lrelu(acc.w * inv + b.w, 0.01f);
  *(float4*)(outp + (size_t)n * 32 + (j << 2)) = o;
}

// ---- layer-4 aggregation: aggregate h3 per head (agg-then-transform) ----
__global__ __launch_bounds__(256) void k_agg4(const int* __restrict__ row_off,
                                              const int* __restrict__ csr_src,
                                              const unsigned long long* __restrict__ aepack,
                                              const float* __restrict__ h3,
                                              const float* __restrict__ ssrc,
                                              const float* __restrict__ sdst,
                                              float* __restrict__ agg) {
  int t = threadIdx.x;
  int g = t >> 3, j = t & 7;
  int n = blockIdx.x * 32 + g;
  if (n >= NN) return;
  float4 sdv = ((const float4*)sdst)[n];
  float sda[4] = {sdv.x, sdv.y, sdv.z, sdv.w};
  int e0 = row_off[n], e1 = row_off[n + 1];
  float m[4], den[4];
  float4 acc[4];
#pragma unroll
  for (int h = 0; h < 4; h++) {
    m[h] = -1e30f;
    den[h] = 0.f;
    acc[h] = make_float4(0.f, 0.f, 0.f, 0.f);
  }
  for (int e = e0; e < e1; ++e) {
    int src = csr_src[e];
    unsigned long long pk = aepack[e];
    float4 ssv = ((const float4*)ssrc)[src];
    float ssa[4] = {ssv.x, ssv.y, ssv.z, ssv.w};
    float4 hv = *(const float4*)(h3 + (size_t)src * 32 + (j << 2));
#pragma unroll
    for (int h = 0; h < 4; h++) {
      float al = ssa[h] + sda[h] + bf2f((unsigned short)(pk >> (16 * h)));
      al = lrelu(al, 0.2f);
      float nm = fmaxf(m[h], al);
      float c1 = __expf(m[h] - nm);
      float p = __expf(al - nm);
      den[h] = den[h] * c1 + p;
      acc[h].x = acc[h].x * c1 + p * hv.x;
      acc[h].y = acc[h].y * c1 + p * hv.y;
      acc[h].z = acc[h].z * c1 + p * hv.z;
      acc[h].w = acc[h].w * c1 + p * hv.w;
      m[h] = nm;
    }
  }
#pragma unroll
  for (int h = 0; h < 4; h++) {
    float inv = 1.f / (den[h] + 1e-16f);
    *(float4*)(agg + (size_t)n * 128 + h * 32 + (j << 2)) =
        make_float4(acc[h].x * inv, acc[h].y * inv, acc[h].z * inv, acc[h].w * inv);
  }
}

// ---- layer-4 epilogue: [N,128] @ W4p[128,64] + b4, lrelu -> h4 ----
__global__ __launch_bounds__(256) void k_epi4(const float* __restrict__ agg,
                                              const float* __restrict__ sm,
                                              const float* __restrict__ b4,
                                              float* __restrict__ h4) {
  __shared__ float4 sW[2048];
  __shared__ float sb[64];
  int t = threadIdx.x;
  for (int i = t; i < 2048; i += 256) sW[i] = ((const float4*)(sm + SM_W4P))[i];
  if (t < 64) sb[t] = b4[t];
  __syncthreads();
  int n = blockIdx.x * 256 + t;
  if (n >= NN) return;
  float acc[64];
#pragma unroll
  for (int j = 0; j < 64; j++) acc[j] = 0.f;
  const float* r = agg + (size_t)n * 128;
  for (int k = 0; k < 128; k += 4) {
    float4 v = *(const float4*)(r + k);
    float va[4] = {v.x, v.y, v.z, v.w};
#pragma unroll
    for (int kk = 0; kk < 4; kk++) {
#pragma unroll
      for (int j4 = 0; j4 < 16; j4++) {
        float4 wv = sW[(k + kk) * 16 + j4];
        acc[j4 * 4 + 0] += va[kk] * wv.x;
        acc[j4 * 4 + 1] += va[kk] * wv.y;
        acc[j4 * 4 + 2] += va[kk] * wv.z;
        acc[j4 * 4 + 3] += va[kk] * wv.w;
      }
    }
  }
  float* o = h4 + (size_t)n * 64;
#pragma unroll
  for (int j4 = 0; j4 < 16; j4++) {
    float4 ov;
    ov.x = lrelu(acc[j4 * 4 + 0] + sb[j4 * 4 + 0], 0.01f);
    ov.y = lrelu(acc[j4 * 4 + 1] + sb[j4 * 4 + 1], 0.01f);
    ov.z = lrelu(acc[j4 * 4 + 2] + sb[j4 * 4 + 2], 0.01f);
    ov.w = lrelu(acc[j4 * 4 + 3] + sb[j4 * 4 + 3], 0.01f);
    ((float4*)o)[j4] = ov;
  }
}

// ---- pooling ----
__global__ __launch_bounds__(256) void k_pool1(const float* __restrict__ h4,
                                               const int* __restrict__ sidx,
                                               float* __restrict__ pool1) {
  int i = blockIdx.x * 256 + threadIdx.x;
  if (i >= NN * 64) return;
  int n = i >> 6, c = i & 63;
  atomicAdd(&pool1[(size_t)sidx[n] * 64 + c], h4[i]);
}

__global__ __launch_bounds__(256) void k_pool2(const float* __restrict__ pool1,
                                               const float* __restrict__ snorm,
                                               const int* __restrict__ nodes,
                                               float* __restrict__ pool2) {
  int i = blockIdx.x * 256 + threadIdx.x;
  if (i >= MM * 64) return;
  int mi = i >> 6, c = i & 63;
  float v = pool1[i] / snorm[mi];
  atomicAdd(&pool2[(size_t)nodes[mi] * 64 + c], v);
}

// ---- final head: one wave per group ----
__global__ __launch_bounds__(64) void k_final(const float* __restrict__ pool2,
                                              const float* __restrict__ h4,
                                              const int* __restrict__ dvi,
                                              const float* __restrict__ Wp,
                                              const float* __restrict__ Wt,
                                              const float* __restrict__ Wo,
                                              const float* __restrict__ bo,
                                              float* __restrict__ out) {
  __shared__ float p[64], tt[64];
  int gI = blockIdx.x, j = threadIdx.x;
  p[j] = pool2[gI * 64 + j];
  tt[j] = h4[(size_t)dvi[gI] * 64 + j];
  __syncthreads();
  float f1 = 0.f, f2 = 0.f;
#pragma unroll 8
  for (int c = 0; c < 64; c++) {
    f1 += p[c] * Wp[c * 64 + j];
    f2 += tt[c] * Wt[c * 64 + j];
  }
  f1 = lrelu(f1, 0.01f);
  f2 = lrelu(f2, 0.01f);
  float v = f1 * Wo[j] + f2 * Wo[64 + j];
  for (int off = 32; off > 0; off >>= 1) v += __shfl_down(v, off, 64);
  if (j == 0) out[gI] = v + bo[0];
}

extern "C" void kernel_launch(void* const* d_in, const int* in_sizes, int n_in,
                              void* d_out, int out_size, void* d_ws, size_t ws_size,
                              hipStream_t stream) {
  const float* x = (const float*)d_in[0];
  const int* ei = (const int*)d_in[1];
  const float* ea = (const float*)d_in[2];
  const int* sidx = (const int*)d_in[3];
  const float* snorm = (const float*)d_in[4];
  const int* nodes = (const int*)d_in[5];
  const int* dvi = (const int*)d_in[6];
  const float* W1 = (const float*)d_in[7];
  const float* We1 = (const float*)d_in[8];
  const float* as1 = (const float*)d_in[9];
  const float* ad1 = (const float*)d_in[10];
  const float* ae1 = (const float*)d_in[11];
  const float* b1 = (const float*)d_in[12];
  const float* W2 = (const float*)d_in[13];
  const float* We2 = (const float*)d_in[14];
  const float* as2 = (const float*)d_in[15];
  const float* ad2 = (const float*)d_in[16];
  const float* ae2 = (const float*)d_in[17];
  const float* b2 = (const float*)d_in[18];
  const float* W3 = (const float*)d_in[19];
  const float* We3 = (const float*)d_in[20];
  const float* as3 = (const float*)d_in[21];
  const float* ad3 = (const float*)d_in[22];
  const float* ae3 = (const float*)d_in[23];
  const float* b3 = (const float*)d_in[24];
  const float* W4 = (const float*)d_in[25];
  // const float* We4 = d_in[26]; passed below
  const float* as4 = (const float*)d_in[27];
  const float* ad4 = (const float*)d_in[28];
  const float* ae4 = (const float*)d_in[29];
  const float* b4 = (const float*)d_in[30];
  const float* Wp = (const float*)d_in[31];
  const float* Wt = (const float*)d_in[32];
  const float* Wo = (const float*)d_in[33];
  const float* bo = (const float*)d_in[34];
  float* out = (float*)d_out;

  char* w = (char*)d_ws;
  size_t off = 0;
  auto take = [&](size_t bytes) -> char* {
    char* p = w + off;
    off = (off + bytes + 255) & ~(size_t)255;
    return p;
  };
  int* row_off = (int*)take((size_t)(NN + 1) * 4);
  int* cursor = (int*)take((size_t)NN * 4);
  int* bsum = (int*)take(512 * 4);
  float* sm = (float*)take(SM_TOTAL * 4);
  int* csr_src = (int*)take((size_t)ETOT * 4);
  unsigned long long* aepack = (unsigned long long*)take((size_t)ETOT * 4 * 8);
  float* hx = (float*)take((size_t)NN * 32 * 4);
  float* ssrc = (float*)take((size_t)NN * 4 * 4);
  float* sdst = (float*)take((size_t)NN * 4 * 4);
  float* bufA = (float*)take((size_t)NN * 32 * 4);
  float* bufB = (float*)take((size_t)NN * 32 * 4);
  float* h4 = (float*)take((size_t)NN * 64 * 4);
  float* agg3 = (float*)take((size_t)NN * 128 * 4);
  float* pool1 = (float*)take((size_t)MM * 64 * 4);
  float* pool2 = (float*)take((size_t)GG * 64 * 4);
  if (off > ws_size) return;  // workspace too small -> visible validation failure

  hipMemsetAsync(cursor, 0, (size_t)NN * 4, stream);
  hipMemsetAsync(sm, 0, 64, stream);
  hipMemsetAsync(pool1, 0, (size_t)MM * 64 * 4, stream);
  hipMemsetAsync(pool2, 0, (size_t)GG * 64 * 4, stream);

  k_eamean<<<1024, 256, 0, stream>>>(ea, sm);
  k_count<<<NB_E256, 256, 0, stream>>>(ei, cursor);
  k_scan1<<<NB_N256, 256, 0, stream>>>(cursor, row_off, bsum);
  k_scan2<<<1, 512, 0, stream>>>(bsum);
  k_scan3<<<NB_N256, 256, 0, stream>>>(row_off, cursor, bsum);
  k_pre<<<1, 256, 0, stream>>>(sm, We1, We2, We3, (const float*)d_in[26], ae1, ae2, ae3,
                               ae4, as4, ad4, W4);
  k_fill<<<NB_E256, 256, 0, stream>>>(ei, ea, sm, cursor, csr_src, aepack);

  // layer 1
  k_t<64><<<NB_N256, 256, 0, stream>>>(x, W1, as1, ad1, hx, ssrc, sdst);
  k_agg<<<NB_AGG, 256, 0, stream>>>(row_off, csr_src, aepack, hx, ssrc, sdst, b1, bufA);
  // layer 2
  k_t<32><<<NB_N256, 256, 0, stream>>>(bufA, W2, as2, ad2, hx, ssrc, sdst);
  k_agg<<<NB_AGG, 256, 0, stream>>>(row_off, csr_src, aepack + (size_t)ETOT, hx, ssrc,
                                    sdst, b2, bufB);
  // layer 3
  k_t<32><<<NB_N256, 256, 0, stream>>>(bufB, W3, as3, ad3, hx, ssrc, sdst);
  k_agg<<<NB_AGG, 256, 0, stream>>>(row_off, csr_src, aepack + 2 * (size_t)ETOT, hx,
                                    ssrc, sdst, b3, bufA);
  // layer 4
  k_t4<<<NB_N256, 256, 0, stream>>>(bufA, sm, ssrc, sdst);
  k_agg4<<<NB_AGG, 256, 0, stream>>>(row_off, csr_src, aepack + 3 * (size_t)ETOT, bufA,
                                     ssrc, sdst, agg3);
  k_epi4<<<NB_N256, 256, 0, stream>>>(agg3, sm, b4, h4);

  // pooling head
  k_pool1<<<(NN * 64) / 256, 256, 0, stream>>>(h4, sidx, pool1);
  k_pool2<<<(MM * 64) / 256, 256, 0, stream>>>(pool1, snorm, nodes, pool2);
  k_final<<<GG, 64, 0, stream>>>(pool2, h4, dvi, Wp, Wt, Wo, bo, out);
}